// Round 1
// baseline (958.247 us; speedup 1.0000x reference)
//
#include <hip/hip_runtime.h>

// Problem constants
#define T_SEQ 2048
#define D_EMB 2048
#define NHEAD 16
#define HS    128
#define NVOC  32000

typedef __attribute__((ext_vector_type(8))) short bf16x8;
typedef __attribute__((ext_vector_type(4))) float f32x4;
typedef unsigned short bfu;   // bf16 bits

__device__ __forceinline__ f32x4 mfma16(bf16x8 a, bf16x8 b, f32x4 c) {
    return __builtin_amdgcn_mfma_f32_16x16x32_bf16(a, b, c, 0, 0, 0);
}

// fp32 -> bf16 RNE
__device__ __forceinline__ bfu f2bu(float f) {
    unsigned int u = __float_as_uint(f);
    unsigned int r = (u + 0x7fffu + ((u >> 16) & 1u)) >> 16;
    return (bfu)r;
}

// async global->LDS, 16B per lane; lds base must be wave-uniform (HW adds lane*16)
__device__ __forceinline__ void async_copy16(void* lds, const void* g) {
    __builtin_amdgcn_global_load_lds(
        (const __attribute__((address_space(1))) unsigned int*)g,
        (__attribute__((address_space(3))) unsigned int*)lds, 16, 0, 0);
}

// ---------------------------------------------------------------------------
// x = we[ids] + pe ; also bf16 copy.  grid = T_SEQ blocks x 256
// ---------------------------------------------------------------------------
__global__ void k_embed(const int* __restrict__ ids, const float* __restrict__ we,
                        const float* __restrict__ pe, float* __restrict__ x,
                        bfu* __restrict__ xb) {
    const int t = blockIdx.x;
    const int row = ids[t];
    const float4* wr = (const float4*)(we + (size_t)row * D_EMB);
    const float4* pr = (const float4*)(pe + (size_t)t * D_EMB);
    float4* xr = (float4*)(x + (size_t)t * D_EMB);
    bfu* xbr = xb + (size_t)t * D_EMB;
    int i = threadIdx.x;
#pragma unroll
    for (int r = 0; r < 2; ++r, i += 256) {
        float4 a = wr[i], b = pr[i];
        float4 s; s.x = a.x + b.x; s.y = a.y + b.y; s.z = a.z + b.z; s.w = a.w + b.w;
        xr[i] = s;
        ushort4 u; u.x = f2bu(s.x); u.y = f2bu(s.y); u.z = f2bu(s.z); u.w = f2bu(s.w);
        *(ushort4*)(xbr + i * 4) = u;
    }
}

// ---------------------------------------------------------------------------
// Transpose+convert: in fp32 [R][C] -> out bf16 [C][R], scaled. Batched on z.
// grid = (C/64, R/64, B), block = 256
// ---------------------------------------------------------------------------
__global__ void k_transpose_cvt(const float* __restrict__ in, bfu* __restrict__ out,
                                int R, int C, float scale) {
    __shared__ float tile[64][65];
    const int z = blockIdx.z;
    in  += (size_t)z * R * C;
    out += (size_t)z * R * C;
    const int r0 = blockIdx.y * 64, c0 = blockIdx.x * 64;
    const int t = threadIdx.x;
#pragma unroll
    for (int it = 0; it < 4; ++it) {
        int fi = it * 256 + t;
        int row = fi >> 4, c4 = (fi & 15) * 4;
        float4 v = *(const float4*)(in + (size_t)(r0 + row) * C + c0 + c4);
        tile[row][c4]     = v.x; tile[row][c4 + 1] = v.y;
        tile[row][c4 + 2] = v.z; tile[row][c4 + 3] = v.w;
    }
    __syncthreads();
#pragma unroll
    for (int it = 0; it < 4; ++it) {
        int ci = it * 256 + t;
        int oc = ci >> 4, r4 = (ci & 15) * 4;
        ushort4 u;
        u.x = f2bu(tile[r4 + 0][oc] * scale);
        u.y = f2bu(tile[r4 + 1][oc] * scale);
        u.z = f2bu(tile[r4 + 2][oc] * scale);
        u.w = f2bu(tile[r4 + 3][oc] * scale);
        *(ushort4*)(out + (size_t)(c0 + oc) * R + r0 + r4) = u;
    }
}

// ---------------------------------------------------------------------------
// GEMM C[M][N] = A[M][K] * Bt[N][K]^T  (both bf16 row-major, lda=ldb=K)
// EPI: 0 = bf16 out; 1 = bf16 out + bias[col] + res32[idx]; 2 = f32 out + bias
// 128x128 tile, BK=64, 4 waves (2x2), 4x4 16x16x32 frags per wave.
// ---------------------------------------------------------------------------
template <int EPI>
__global__ __launch_bounds__(256, 2)
void k_gemm_nt(const bfu* __restrict__ A, const bfu* __restrict__ Bt,
               void* __restrict__ Cv, const float* __restrict__ bias,
               const float* __restrict__ res32, int M, int N, int K) {
    __shared__ __align__(16) char smem[2 * 128 * 64 * 2];
    const int tid = threadIdx.x;
    const int w = tid >> 6, lane = tid & 63;
    const int wr = w >> 1, wc = w & 1;
    const int lr = lane & 15, lk = lane >> 4;   // lk in 0..3
    const int mb = M >> 7;
    const int m0 = (blockIdx.x % mb) << 7;
    const int n0 = (blockIdx.x / mb) << 7;
    char* As = smem;
    char* Bs = smem + 16384;
    f32x4 acc[4][4];
#pragma unroll
    for (int i = 0; i < 4; ++i)
#pragma unroll
        for (int j = 0; j < 4; ++j) acc[i][j] = (f32x4){0.f, 0.f, 0.f, 0.f};

    const bfu* Ag = A + (size_t)m0 * K;
    const bfu* Bg = Bt + (size_t)n0 * K;

    for (int kk = 0; kk < K; kk += 64) {
        __syncthreads();
#pragma unroll
        for (int r = 0; r < 4; ++r) {
            int i = r * 256 + tid;                       // lane-load index
            async_copy16(As + (r * 256 + w * 64) * 16,
                         Ag + (size_t)(i >> 3) * K + kk + (i & 7) * 8);
        }
#pragma unroll
        for (int r = 0; r < 4; ++r) {
            int i = r * 256 + tid;
            async_copy16(Bs + (r * 256 + w * 64) * 16,
                         Bg + (size_t)(i >> 3) * K + kk + (i & 7) * 8);
        }
        __syncthreads();
#pragma unroll
        for (int kc = 0; kc < 2; ++kc) {
            bf16x8 a[4], b[4];
#pragma unroll
            for (int mf = 0; mf < 4; ++mf)
                a[mf] = *(const bf16x8*)(As + ((wr * 64 + mf * 16 + lr) * 64 + kc * 32 + lk * 8) * 2);
#pragma unroll
            for (int nf = 0; nf < 4; ++nf)
                b[nf] = *(const bf16x8*)(Bs + ((wc * 64 + nf * 16 + lr) * 64 + kc * 32 + lk * 8) * 2);
#pragma unroll
            for (int mf = 0; mf < 4; ++mf)
#pragma unroll
                for (int nf = 0; nf < 4; ++nf)
                    acc[mf][nf] = mfma16(a[mf], b[nf], acc[mf][nf]);
        }
    }
    // epilogue: C row = (lane>>4)*4 + j, col = lane&15  (m89-verified layout)
#pragma unroll
    for (int nf = 0; nf < 4; ++nf) {
        int col = n0 + wc * 64 + nf * 16 + lr;
        float bv = (EPI >= 1) ? bias[col] : 0.0f;
#pragma unroll
        for (int mf = 0; mf < 4; ++mf) {
            int row0 = m0 + wr * 64 + mf * 16 + lk * 4;
            f32x4 v = acc[mf][nf];
#pragma unroll
            for (int j = 0; j < 4; ++j) {
                size_t idx = (size_t)(row0 + j) * N + col;
                float val = v[j] + bv;
                if (EPI == 1) val += res32[idx];
                if (EPI == 2) ((float*)Cv)[idx] = val;
                else          ((bfu*)Cv)[idx] = f2bu(val);
            }
        }
    }
}

// ---------------------------------------------------------------------------
// Flash attention (causal). q,k: [T][H*HS] bf16 (scale folded into q via WqT).
// vT: [H*HS][T] bf16. out: [T][H*HS] bf16.
// grid = (T/64, H), 256 threads = 4 independent waves, 16 q-rows per wave.
// K/V read direct from global (L2-resident, 512KB/head) — no barriers at all.
// ---------------------------------------------------------------------------
__global__ __launch_bounds__(256, 2)
void k_attn(const bfu* __restrict__ q, const bfu* __restrict__ k,
            const bfu* __restrict__ vT, bfu* __restrict__ o) {
    __shared__ __align__(16) bfu plds[4][16][72];   // per-wave P tile, padded stride
    const int w = threadIdx.x >> 6, lane = threadIdx.x & 63;
    const int lr = lane & 15, lk = lane >> 4;
    const int h = blockIdx.y;
    const int qrow = blockIdx.x * 64 + w * 16;

    bf16x8 aq[4];
#pragma unroll
    for (int kc = 0; kc < 4; ++kc)
        aq[kc] = *(const bf16x8*)(q + (size_t)(qrow + lr) * D_EMB + h * HS + kc * 32 + lk * 8);

    f32x4 O[8];
#pragma unroll
    for (int hf = 0; hf < 8; ++hf) O[hf] = (f32x4){0.f, 0.f, 0.f, 0.f};
    float m_[4], l_[4];
#pragma unroll
    for (int j = 0; j < 4; ++j) { m_[j] = -__builtin_inff(); l_[j] = 0.f; }

    const int nst = (qrow + 15) / 64 + 1;
    for (int st = 0; st < nst; ++st) {
        const int s0 = st * 64;
        f32x4 S[4];
#pragma unroll
        for (int nf = 0; nf < 4; ++nf) S[nf] = (f32x4){0.f, 0.f, 0.f, 0.f};
#pragma unroll
        for (int nf = 0; nf < 4; ++nf)
#pragma unroll
            for (int kc = 0; kc < 4; ++kc) {
                bf16x8 bk = *(const bf16x8*)(k + (size_t)(s0 + nf * 16 + lr) * D_EMB + h * HS + kc * 32 + lk * 8);
                S[nf] = mfma16(aq[kc], bk, S[nf]);
            }
        if (s0 + 63 > qrow) {   // causal mask on boundary tiles
#pragma unroll
            for (int nf = 0; nf < 4; ++nf) {
                int scol = s0 + nf * 16 + lr;
#pragma unroll
                for (int j = 0; j < 4; ++j)
                    if (scol > qrow + lk * 4 + j) S[nf][j] = -1e30f;
            }
        }
        float tm[4];
#pragma unroll
        for (int j = 0; j < 4; ++j)
            tm[j] = fmaxf(fmaxf(S[0][j], S[1][j]), fmaxf(S[2][j], S[3][j]));
#pragma unroll
        for (int d = 1; d < 16; d <<= 1)
#pragma unroll
            for (int j = 0; j < 4; ++j) tm[j] = fmaxf(tm[j], __shfl_xor(tm[j], d));
        float mn[4], ts[4];
#pragma unroll
        for (int j = 0; j < 4; ++j) mn[j] = fmaxf(m_[j], tm[j]);
#pragma unroll
        for (int nf = 0; nf < 4; ++nf)
#pragma unroll
            for (int j = 0; j < 4; ++j) S[nf][j] = __expf(S[nf][j] - mn[j]);
#pragma unroll
        for (int j = 0; j < 4; ++j) ts[j] = S[0][j] + S[1][j] + S[2][j] + S[3][j];
#pragma unroll
        for (int d = 1; d < 16; d <<= 1)
#pragma unroll
            for (int j = 0; j < 4; ++j) ts[j] += __shfl_xor(ts[j], d);
        // stash P (bf16) in per-wave LDS in MFMA-A layout order
#pragma unroll
        for (int nf = 0; nf < 4; ++nf)
#pragma unroll
            for (int j = 0; j < 4; ++j)
                plds[w][lk * 4 + j][nf * 16 + lr] = f2bu(S[nf][j]);
        // online-softmax state + O rescale
#pragma unroll
        for (int j = 0; j < 4; ++j) {
            float f = __expf(m_[j] - mn[j]);
            l_[j] = l_[j] * f + ts[j];
            m_[j] = mn[j];
#pragma unroll
            for (int hf = 0; hf < 8; ++hf) O[hf][j] *= f;
        }
        bf16x8 pa[2];
#pragma unroll
        for (int kc2 = 0; kc2 < 2; ++kc2)
            pa[kc2] = *(const bf16x8*)(&plds[w][lr][kc2 * 32 + lk * 8]);
#pragma unroll
        for (int hf = 0; hf < 8; ++hf)
#pragma unroll
            for (int kc2 = 0; kc2 < 2; ++kc2) {
                bf16x8 bv = *(const bf16x8*)(vT + (size_t)(h * HS + hf * 16 + lr) * T_SEQ + s0 + kc2 * 32 + lk * 8);
                O[hf] = mfma16(pa[kc2], bv, O[hf]);
            }
    }
#pragma unroll
    for (int j = 0; j < 4; ++j) {
        float inv = 1.0f / l_[j];
        size_t rbase = (size_t)(qrow + lk * 4 + j) * D_EMB + h * HS;
#pragma unroll
        for (int hf = 0; hf < 8; ++hf)
            o[rbase + hf * 16 + lr] = f2bu(O[hf][j] * inv);
    }
}

// ---------------------------------------------------------------------------
extern "C" void kernel_launch(void* const* d_in, const int* in_sizes, int n_in,
                              void* d_out, int out_size, void* d_ws, size_t ws_size,
                              hipStream_t stream) {
    const int*   ids   = (const int*)d_in[0];
    const float* we    = (const float*)d_in[1];
    const float* pe    = (const float*)d_in[2];
    const float* Wq    = (const float*)d_in[3];
    const float* Wk    = (const float*)d_in[4];
    const float* Wv    = (const float*)d_in[5];
    const float* projw = (const float*)d_in[6];
    const float* projb = (const float*)d_in[7];
    const float* fcw   = (const float*)d_in[8];
    const float* fcb   = (const float*)d_in[9];
    float* out = (float*)d_out;
    (void)in_sizes; (void)n_in; (void)out_size; (void)ws_size;

    char* ws = (char*)d_ws;
    size_t off = 0;
    bfu*   fcwT  = (bfu*)(ws + off);  off += (size_t)NVOC * D_EMB * 2;   // 131 MB
    float* x32   = (float*)(ws + off); off += (size_t)T_SEQ * D_EMB * 4; // 16 MB
    bfu*   xb    = (bfu*)(ws + off);  off += (size_t)T_SEQ * D_EMB * 2;  // also attn-out
    bfu*   qb    = (bfu*)(ws + off);  off += (size_t)T_SEQ * D_EMB * 2;  // also resid
    bfu*   kb    = (bfu*)(ws + off);  off += (size_t)T_SEQ * D_EMB * 2;
    bfu*   vTb   = (bfu*)(ws + off);  off += (size_t)T_SEQ * D_EMB * 2;
    bfu*   WqT   = (bfu*)(ws + off);  off += (size_t)D_EMB * HS * NHEAD * 2;
    bfu*   WkT   = (bfu*)(ws + off);  off += (size_t)D_EMB * HS * NHEAD * 2;
    bfu*   WvT   = (bfu*)(ws + off);  off += (size_t)D_EMB * HS * NHEAD * 2;
    bfu*   projT = (bfu*)(ws + off);  off += (size_t)D_EMB * D_EMB * 2;  // ~205 MB total

    const float qscale = 0.08838834764831845f;  // 1/sqrt(HS), folded into WqT

    // weight transpose+convert (B^T-form bf16)
    k_transpose_cvt<<<dim3(HS / 64, D_EMB / 64, NHEAD), 256, 0, stream>>>(Wq, WqT, D_EMB, HS, qscale);
    k_transpose_cvt<<<dim3(HS / 64, D_EMB / 64, NHEAD), 256, 0, stream>>>(Wk, WkT, D_EMB, HS, 1.0f);
    k_transpose_cvt<<<dim3(HS / 64, D_EMB / 64, NHEAD), 256, 0, stream>>>(Wv, WvT, D_EMB, HS, 1.0f);
    k_transpose_cvt<<<dim3(D_EMB / 64, D_EMB / 64, 1), 256, 0, stream>>>(projw, projT, D_EMB, D_EMB, 1.0f);
    k_transpose_cvt<<<dim3(NVOC / 64, D_EMB / 64, 1), 256, 0, stream>>>(fcw, fcwT, D_EMB, NVOC, 1.0f);

    // x = we[ids] + pe
    k_embed<<<T_SEQ, 256, 0, stream>>>(ids, we, pe, x32, xb);

    // QKV projections (q pre-scaled via WqT)
    k_gemm_nt<0><<<(T_SEQ / 128) * (D_EMB / 128), 256, 0, stream>>>(xb, WqT, qb, nullptr, nullptr, T_SEQ, D_EMB, D_EMB);
    k_gemm_nt<0><<<(T_SEQ / 128) * (D_EMB / 128), 256, 0, stream>>>(xb, WkT, kb, nullptr, nullptr, T_SEQ, D_EMB, D_EMB);
    k_gemm_nt<0><<<(D_EMB / 128) * (T_SEQ / 128), 256, 0, stream>>>(WvT, xb, vTb, nullptr, nullptr, D_EMB, T_SEQ, D_EMB);

    // attention -> xb (cat layout [T][H*HS])
    k_attn<<<dim3(T_SEQ / 64, NHEAD), 256, 0, stream>>>(qb, kb, vTb, xb);

    // proj + bias + residual -> resid (bf16, into qb)
    k_gemm_nt<1><<<(T_SEQ / 128) * (D_EMB / 128), 256, 0, stream>>>(xb, projT, qb, projb, x32, T_SEQ, D_EMB, D_EMB);

    // final vocab GEMM (fp32 out + bias)
    k_gemm_nt<2><<<(T_SEQ / 128) * (NVOC / 128), 256, 0, stream>>>(qb, fcwT, out, fcb, nullptr, T_SEQ, NVOC, D_EMB);
}

// Round 3
// 915.233 us; speedup vs baseline: 1.0470x; 1.0470x over previous
//
#include <hip/hip_runtime.h>

// Problem constants
#define T_SEQ 2048
#define D_EMB 2048
#define NHEAD 16
#define HS    128
#define NVOC  32000

typedef __attribute__((ext_vector_type(8))) short bf16x8;
typedef __attribute__((ext_vector_type(4))) float f32x4;
typedef unsigned short bfu;   // bf16 bits

__device__ __forceinline__ f32x4 mfma16(bf16x8 a, bf16x8 b, f32x4 c) {
    return __builtin_amdgcn_mfma_f32_16x16x32_bf16(a, b, c, 0, 0, 0);
}

// fp32 -> bf16 RNE
__device__ __forceinline__ bfu f2bu(float f) {
    unsigned int u = __float_as_uint(f);
    unsigned int r = (u + 0x7fffu + ((u >> 16) & 1u)) >> 16;
    return (bfu)r;
}

// async global->LDS, 16B per lane; lds base must be wave-uniform (HW adds lane*16)
__device__ __forceinline__ void async_copy16(void* lds, const void* g) {
    __builtin_amdgcn_global_load_lds(
        (const __attribute__((address_space(1))) unsigned int*)g,
        (__attribute__((address_space(3))) unsigned int*)lds, 16, 0, 0);
}

#define SB0 __builtin_amdgcn_sched_barrier(0)
#define BARRIER __builtin_amdgcn_s_barrier()
#define WAIT_LGKM0 asm volatile("s_waitcnt lgkmcnt(0)" ::: "memory")
#define WAIT_VM8   asm volatile("s_waitcnt vmcnt(8)" ::: "memory")
#define WAIT_VM6   asm volatile("s_waitcnt vmcnt(6)" ::: "memory")
#define WAIT_VM4   asm volatile("s_waitcnt vmcnt(4)" ::: "memory")
#define WAIT_VM2   asm volatile("s_waitcnt vmcnt(2)" ::: "memory")
#define WAIT_VM0   asm volatile("s_waitcnt vmcnt(0)" ::: "memory")

// ---------------------------------------------------------------------------
// x = we[ids] + pe ; also bf16 copy.  grid = T_SEQ blocks x 256
// ---------------------------------------------------------------------------
__global__ void k_embed(const int* __restrict__ ids, const float* __restrict__ we,
                        const float* __restrict__ pe, float* __restrict__ x,
                        bfu* __restrict__ xb) {
    const int t = blockIdx.x;
    const int row = ids[t];
    const float4* wr = (const float4*)(we + (size_t)row * D_EMB);
    const float4* pr = (const float4*)(pe + (size_t)t * D_EMB);
    float4* xr = (float4*)(x + (size_t)t * D_EMB);
    bfu* xbr = xb + (size_t)t * D_EMB;
    int i = threadIdx.x;
#pragma unroll
    for (int r = 0; r < 2; ++r, i += 256) {
        float4 a = wr[i], b = pr[i];
        float4 s; s.x = a.x + b.x; s.y = a.y + b.y; s.z = a.z + b.z; s.w = a.w + b.w;
        xr[i] = s;
        ushort4 u; u.x = f2bu(s.x); u.y = f2bu(s.y); u.z = f2bu(s.z); u.w = f2bu(s.w);
        *(ushort4*)(xbr + i * 4) = u;
    }
}

// ---------------------------------------------------------------------------
// Transpose+convert: in fp32 [R][C] -> out bf16 [C][R], scaled. Batched on z.
// ---------------------------------------------------------------------------
__global__ void k_transpose_cvt(const float* __restrict__ in, bfu* __restrict__ out,
                                int R, int C, float scale) {
    __shared__ float tile[64][65];
    const int z = blockIdx.z;
    in  += (size_t)z * R * C;
    out += (size_t)z * R * C;
    const int r0 = blockIdx.y * 64, c0 = blockIdx.x * 64;
    const int t = threadIdx.x;
#pragma unroll
    for (int it = 0; it < 4; ++it) {
        int fi = it * 256 + t;
        int row = fi >> 4, c4 = (fi & 15) * 4;
        float4 v = *(const float4*)(in + (size_t)(r0 + row) * C + c0 + c4);
        tile[row][c4]     = v.x; tile[row][c4 + 1] = v.y;
        tile[row][c4 + 2] = v.z; tile[row][c4 + 3] = v.w;
    }
    __syncthreads();
#pragma unroll
    for (int it = 0; it < 4; ++it) {
        int ci = it * 256 + t;
        int oc = ci >> 4, r4 = (ci & 15) * 4;
        ushort4 u;
        u.x = f2bu(tile[r4 + 0][oc] * scale);
        u.y = f2bu(tile[r4 + 1][oc] * scale);
        u.z = f2bu(tile[r4 + 2][oc] * scale);
        u.w = f2bu(tile[r4 + 3][oc] * scale);
        *(ushort4*)(out + (size_t)(c0 + oc) * R + r0 + r4) = u;
    }
}

// ---------------------------------------------------------------------------
// GEMM (m97-style 128x128) C[M][N] = A[M][K] * Bt[N][K]^T
// EPI: 0 = bf16 out; 1 = bf16 out + bias[col] + res32[idx]; 2 = f32 out + bias
// ---------------------------------------------------------------------------
template <int EPI>
__global__ __launch_bounds__(256, 2)
void k_gemm_nt(const bfu* __restrict__ A, const bfu* __restrict__ Bt,
               void* __restrict__ Cv, const float* __restrict__ bias,
               const float* __restrict__ res32, int M, int N, int K) {
    __shared__ __align__(16) char smem[2 * 128 * 64 * 2];
    const int tid = threadIdx.x;
    const int w = tid >> 6, lane = tid & 63;
    const int wr = w >> 1, wc = w & 1;
    const int lr = lane & 15, lk = lane >> 4;   // lk in 0..3
    const int mb = M >> 7;
    const int m0 = (blockIdx.x % mb) << 7;
    const int n0 = (blockIdx.x / mb) << 7;
    char* As = smem;
    char* Bs = smem + 16384;
    f32x4 acc[4][4];
#pragma unroll
    for (int i = 0; i < 4; ++i)
#pragma unroll
        for (int j = 0; j < 4; ++j) acc[i][j] = (f32x4){0.f, 0.f, 0.f, 0.f};

    const bfu* Ag = A + (size_t)m0 * K;
    const bfu* Bg = Bt + (size_t)n0 * K;

    for (int kk = 0; kk < K; kk += 64) {
        __syncthreads();
#pragma unroll
        for (int r = 0; r < 4; ++r) {
            int i = r * 256 + tid;                       // lane-load index
            async_copy16(As + (r * 256 + w * 64) * 16,
                         Ag + (size_t)(i >> 3) * K + kk + (i & 7) * 8);
        }
#pragma unroll
        for (int r = 0; r < 4; ++r) {
            int i = r * 256 + tid;
            async_copy16(Bs + (r * 256 + w * 64) * 16,
                         Bg + (size_t)(i >> 3) * K + kk + (i & 7) * 8);
        }
        __syncthreads();
#pragma unroll
        for (int kc = 0; kc < 2; ++kc) {
            bf16x8 a[4], b[4];
#pragma unroll
            for (int mf = 0; mf < 4; ++mf)
                a[mf] = *(const bf16x8*)(As + ((wr * 64 + mf * 16 + lr) * 64 + kc * 32 + lk * 8) * 2);
#pragma unroll
            for (int nf = 0; nf < 4; ++nf)
                b[nf] = *(const bf16x8*)(Bs + ((wc * 64 + nf * 16 + lr) * 64 + kc * 32 + lk * 8) * 2);
#pragma unroll
            for (int mf = 0; mf < 4; ++mf)
#pragma unroll
                for (int nf = 0; nf < 4; ++nf)
                    acc[mf][nf] = mfma16(a[mf], b[nf], acc[mf][nf]);
        }
    }
#pragma unroll
    for (int nf = 0; nf < 4; ++nf) {
        int col = n0 + wc * 64 + nf * 16 + lr;
        float bv = (EPI >= 1) ? bias[col] : 0.0f;
#pragma unroll
        for (int mf = 0; mf < 4; ++mf) {
            int row0 = m0 + wr * 64 + mf * 16 + lk * 4;
            f32x4 v = acc[mf][nf];
#pragma unroll
            for (int j = 0; j < 4; ++j) {
                size_t idx = (size_t)(row0 + j) * N + col;
                float val = v[j] + bv;
                if (EPI == 1) val += res32[idx];
                if (EPI == 2) ((float*)Cv)[idx] = val;
                else          ((bfu*)Cv)[idx] = f2bu(val);
            }
        }
    }
}

// ---------------------------------------------------------------------------
// 256x256 8-phase GEMM (T1+T2+T3+T4+T5), f32 out + bias.
// Per-wave vmcnt FIFO invariant: 4 chunks (8 loads) outstanding at every
// phase boundary; each phase issues 1 chunk and vmcnt(8) retires exactly the
// chunk the NEXT phase reads. Last two K-tiles peeled with decreasing waits
// (6/4/2/0) since they stop issuing — the round-2 bug was vmcnt(8) becoming
// a no-op there, leaving the final K-tile's LDS un-guaranteed.
// ---------------------------------------------------------------------------
__device__ __forceinline__ void stage_chunk(char* sm, const bfu* A_, const bfu* B_,
                                            int K, int tt, int kind, int w,
                                            int laneRow, int laneCol) {
    // kind: 0=A-q0 (rows 0-63,128-191), 1=A-q1 (64-127,192-255),
    //       2=B-q0 (rows x*64+[0,32)), 3=B-q1 (rows x*64+[32,64))
    char* base = sm + (size_t)(tt & 1) * 65536 + ((kind >= 2) ? 32768 : 0);
    const bfu* G = (kind >= 2) ? B_ : A_;
#pragma unroll
    for (int r = 0; r < 2; ++r) {
        int p = w * 2 + r;
        int row0 = (kind < 2) ? ((kind & 1) * 64 + (p & 7) * 8 + (p >> 3) * 128)
                              : ((kind & 1) * 32 + (p & 3) * 8 + (p >> 2) * 64);
        const char* g = (const char*)G + ((size_t)(row0 + laneRow) * K + tt * 64) * 2 + laneCol;
        async_copy16(base + row0 * 128, g);
    }
}

template <int Q>
__device__ __forceinline__ void read_A(bf16x8 (&aA)[2][4][2], const char* bufA,
                                       int wm, int lr, int aswz) {
    const char* p = bufA + ((wm * 128 + Q * 64 + lr) * 128) + aswz;
#pragma unroll
    for (int mf = 0; mf < 4; ++mf)
#pragma unroll
        for (int kc = 0; kc < 2; ++kc)
            aA[Q][mf][kc] = *(const bf16x8*)(p + mf * 2048 + kc * 64);
}

template <int Q>
__device__ __forceinline__ void read_B(bf16x8 (&bB)[2][2], const char* bufB,
                                       int wn, int lr, int aswz) {
    const char* p = bufB + ((wn * 64 + Q * 32 + lr) * 128) + aswz;
#pragma unroll
    for (int nf = 0; nf < 2; ++nf)
#pragma unroll
        for (int kc = 0; kc < 2; ++kc)
            bB[nf][kc] = *(const bf16x8*)(p + nf * 2048 + kc * 64);
}

template <int QM, int QN>
__device__ __forceinline__ void mfma_quad(f32x4 (&acc)[8][4], bf16x8 (&aA)[2][4][2],
                                          bf16x8 (&bB)[2][2]) {
    __builtin_amdgcn_s_setprio(1);
#pragma unroll
    for (int mf = 0; mf < 4; ++mf)
#pragma unroll
        for (int nf = 0; nf < 2; ++nf)
#pragma unroll
            for (int kc = 0; kc < 2; ++kc)
                acc[QM * 4 + mf][QN * 2 + nf] =
                    mfma16(aA[QM][mf][kc], bB[nf][kc], acc[QM * 4 + mf][QN * 2 + nf]);
    __builtin_amdgcn_s_setprio(0);
}

__global__ __launch_bounds__(512, 2)
void k_gemm256(const bfu* __restrict__ A, const bfu* __restrict__ Bt,
               float* __restrict__ C, const float* __restrict__ bias,
               int M, int N, int K) {
    __shared__ __align__(16) char smem[2 * 65536];   // 128 KiB
    const int tid = threadIdx.x;
    const int w = tid >> 6, lane = tid & 63;
    const int wm = w >> 2, wn = w & 3;
    const int lr = lane & 15, lk = lane >> 4;
    const int aswz = (lk * 16) ^ (((lr >> 2) & 1) << 5);              // read-side swz
    const int laneRow = lane >> 3;
    const int laneCol = ((lane & 7) * 16) ^ (((lane >> 5) & 1) << 5); // stage-side swz

    // XCD-aware bijective block swizzle (nwgs % 8 == 0 for our launch)
    const int mb = M >> 8;
    const int nwgs = mb * (N >> 8);
    int bid = blockIdx.x;
    int swz = ((nwgs & 7) == 0) ? ((bid & 7) * (nwgs >> 3) + (bid >> 3)) : bid;
    const int m0 = (swz % mb) << 8;
    const int n0 = (swz / mb) << 8;

    const bfu* Ag = A + (size_t)m0 * K;
    const bfu* Bg = Bt + (size_t)n0 * K;

    f32x4 acc[8][4];
#pragma unroll
    for (int i = 0; i < 8; ++i)
#pragma unroll
        for (int j = 0; j < 4; ++j) acc[i][j] = (f32x4){0.f, 0.f, 0.f, 0.f};
    bf16x8 aA[2][4][2], bB[2][2];

    const int nkt = K >> 6;   // requires nkt >= 4

    // prologue: tile0 all chunks (oldest-first = first-consumed), tile1 B0,A0
    stage_chunk(smem, Ag, Bg, K, 0, 0, w, laneRow, laneCol);
    stage_chunk(smem, Ag, Bg, K, 0, 2, w, laneRow, laneCol);
    stage_chunk(smem, Ag, Bg, K, 0, 1, w, laneRow, laneCol);
    stage_chunk(smem, Ag, Bg, K, 0, 3, w, laneRow, laneCol);
    stage_chunk(smem, Ag, Bg, K, 1, 2, w, laneRow, laneCol);
    stage_chunk(smem, Ag, Bg, K, 1, 0, w, laneRow, laneCol);
    WAIT_VM8; SB0; BARRIER;

    for (int t = 0; t < nkt - 2; ++t) {
        const char* bufA = smem + (size_t)(t & 1) * 65536;
        const char* bufB = bufA + 32768;
        // P0
        read_A<0>(aA, bufA, wm, lr, aswz);
        read_B<0>(bB, bufB, wn, lr, aswz);
        stage_chunk(smem, Ag, Bg, K, t + 1, 1, w, laneRow, laneCol);
        SB0; BARRIER; WAIT_LGKM0; SB0;
        mfma_quad<0, 0>(acc, aA, bB);
        WAIT_VM8; SB0; BARRIER;
        // P1
        read_A<1>(aA, bufA, wm, lr, aswz);
        stage_chunk(smem, Ag, Bg, K, t + 1, 3, w, laneRow, laneCol);
        SB0; BARRIER; WAIT_LGKM0; SB0;
        mfma_quad<1, 0>(acc, aA, bB);
        WAIT_VM8; SB0; BARRIER;
        // P2
        read_B<1>(bB, bufB, wn, lr, aswz);
        stage_chunk(smem, Ag, Bg, K, t + 2, 2, w, laneRow, laneCol);
        SB0; BARRIER; WAIT_LGKM0; SB0;
        mfma_quad<0, 1>(acc, aA, bB);
        WAIT_VM8; SB0; BARRIER;
        // P3
        stage_chunk(smem, Ag, Bg, K, t + 2, 0, w, laneRow, laneCol);
        SB0; BARRIER; SB0;
        mfma_quad<1, 1>(acc, aA, bB);
        WAIT_VM8; SB0; BARRIER;
    }

    {   // t = nkt-2: last tile that stages (t+1 only); waits 8,8,6,4
        const int t = nkt - 2;
        const char* bufA = smem + (size_t)(t & 1) * 65536;
        const char* bufB = bufA + 32768;
        read_A<0>(aA, bufA, wm, lr, aswz);
        read_B<0>(bB, bufB, wn, lr, aswz);
        stage_chunk(smem, Ag, Bg, K, t + 1, 1, w, laneRow, laneCol);
        SB0; BARRIER; WAIT_LGKM0; SB0;
        mfma_quad<0, 0>(acc, aA, bB);
        WAIT_VM8; SB0; BARRIER;

        read_A<1>(aA, bufA, wm, lr, aswz);
        stage_chunk(smem, Ag, Bg, K, t + 1, 3, w, laneRow, laneCol);
        SB0; BARRIER; WAIT_LGKM0; SB0;
        mfma_quad<1, 0>(acc, aA, bB);
        WAIT_VM8; SB0; BARRIER;

        read_B<1>(bB, bufB, wn, lr, aswz);
        SB0; BARRIER; WAIT_LGKM0; SB0;
        mfma_quad<0, 1>(acc, aA, bB);
        WAIT_VM6; SB0; BARRIER;

        SB0;
        mfma_quad<1, 1>(acc, aA, bB);
        WAIT_VM4; SB0; BARRIER;
    }
    {   // t = nkt-1: drain; waits 2,0
        const int t = nkt - 1;
        const char* bufA = smem + (size_t)(t & 1) * 65536;
        const char* bufB = bufA + 32768;
        read_A<0>(aA, bufA, wm, lr, aswz);
        read_B<0>(bB, bufB, wn, lr, aswz);
        SB0; BARRIER; WAIT_LGKM0; SB0;
        mfma_quad<0, 0>(acc, aA, bB);
        WAIT_VM2; SB0; BARRIER;

        read_A<1>(aA, bufA, wm, lr, aswz);
        SB0; BARRIER; WAIT_LGKM0; SB0;
        mfma_quad<1, 0>(acc, aA, bB);
        WAIT_VM0; SB0; BARRIER;

        read_B<1>(bB, bufB, wn, lr, aswz);
        SB0; WAIT_LGKM0; SB0;
        mfma_quad<0, 1>(acc, aA, bB);
        mfma_quad<1, 1>(acc, aA, bB);
    }

    // epilogue: f32 + bias
#pragma unroll
    for (int nfg = 0; nfg < 4; ++nfg) {
        int col = n0 + wn * 64 + nfg * 16 + lr;
        float bv = bias[col];
#pragma unroll
        for (int mfg = 0; mfg < 8; ++mfg) {
            int row0 = m0 + wm * 128 + mfg * 16 + lk * 4;
            f32x4 v = acc[mfg][nfg];
#pragma unroll
            for (int j = 0; j < 4; ++j)
                C[(size_t)(row0 + j) * N + col] = v[j] + bv;
        }
    }
}

// ---------------------------------------------------------------------------
// Flash attention (causal). q,k: [T][H*HS] bf16 (scale folded into q via WqT).
// vT: [H*HS][T] bf16. out: [T][H*HS] bf16.
// ---------------------------------------------------------------------------
__global__ __launch_bounds__(256, 2)
void k_attn(const bfu* __restrict__ q, const bfu* __restrict__ k,
            const bfu* __restrict__ vT, bfu* __restrict__ o) {
    __shared__ __align__(16) bfu plds[4][16][72];   // per-wave P tile, padded stride
    const int w = threadIdx.x >> 6, lane = threadIdx.x & 63;
    const int lr = lane & 15, lk = lane >> 4;
    const int h = blockIdx.y;
    const int qrow = blockIdx.x * 64 + w * 16;

    bf16x8 aq[4];
#pragma unroll
    for (int kc = 0; kc < 4; ++kc)
        aq[kc] = *(const bf16x8*)(q + (size_t)(qrow + lr) * D_EMB + h * HS + kc * 32 + lk * 8);

    f32x4 O[8];
#pragma unroll
    for (int hf = 0; hf < 8; ++hf) O[hf] = (f32x4){0.f, 0.f, 0.f, 0.f};
    float m_[4], l_[4];
#pragma unroll
    for (int j = 0; j < 4; ++j) { m_[j] = -__builtin_inff(); l_[j] = 0.f; }

    const int nst = (qrow + 15) / 64 + 1;
    for (int st = 0; st < nst; ++st) {
        const int s0 = st * 64;
        f32x4 S[4];
#pragma unroll
        for (int nf = 0; nf < 4; ++nf) S[nf] = (f32x4){0.f, 0.f, 0.f, 0.f};
#pragma unroll
        for (int nf = 0; nf < 4; ++nf)
#pragma unroll
            for (int kc = 0; kc < 4; ++kc) {
                bf16x8 bk = *(const bf16x8*)(k + (size_t)(s0 + nf * 16 + lr) * D_EMB + h * HS + kc * 32 + lk * 8);
                S[nf] = mfma16(aq[kc], bk, S[nf]);
            }
        if (s0 + 63 > qrow) {
#pragma unroll
            for (int nf = 0; nf < 4; ++nf) {
                int scol = s0 + nf * 16 + lr;
#pragma unroll
                for (int j = 0; j < 4; ++j)
                    if (scol > qrow + lk * 4 + j) S[nf][j] = -1e30f;
            }
        }
        float tm[4];
#pragma unroll
        for (int j = 0; j < 4; ++j)
            tm[j] = fmaxf(fmaxf(S[0][j], S[1][j]), fmaxf(S[2][j], S[3][j]));
#pragma unroll
        for (int d = 1; d < 16; d <<= 1)
#pragma unroll
            for (int j = 0; j < 4; ++j) tm[j] = fmaxf(tm[j], __shfl_xor(tm[j], d));
        float mn[4], ts[4];
#pragma unroll
        for (int j = 0; j < 4; ++j) mn[j] = fmaxf(m_[j], tm[j]);
#pragma unroll
        for (int nf = 0; nf < 4; ++nf)
#pragma unroll
            for (int j = 0; j < 4; ++j) S[nf][j] = __expf(S[nf][j] - mn[j]);
#pragma unroll
        for (int j = 0; j < 4; ++j) ts[j] = S[0][j] + S[1][j] + S[2][j] + S[3][j];
#pragma unroll
        for (int d = 1; d < 16; d <<= 1)
#pragma unroll
            for (int j = 0; j < 4; ++j) ts[j] += __shfl_xor(ts[j], d);
#pragma unroll
        for (int nf = 0; nf < 4; ++nf)
#pragma unroll
            for (int j = 0; j < 4; ++j)
                plds[w][lk * 4 + j][nf * 16 + lr] = f2bu(S[nf][j]);
#pragma unroll
        for (int j = 0; j < 4; ++j) {
            float f = __expf(m_[j] - mn[j]);
            l_[j] = l_[j] * f + ts[j];
            m_[j] = mn[j];
#pragma unroll
            for (int hf = 0; hf < 8; ++hf) O[hf][j] *= f;
        }
        bf16x8 pa[2];
#pragma unroll
        for (int kc2 = 0; kc2 < 2; ++kc2)
            pa[kc2] = *(const bf16x8*)(&plds[w][lr][kc2 * 32 + lk * 8]);
#pragma unroll
        for (int hf = 0; hf < 8; ++hf)
#pragma unroll
            for (int kc2 = 0; kc2 < 2; ++kc2) {
                bf16x8 bv = *(const bf16x8*)(vT + (size_t)(h * HS + hf * 16 + lr) * T_SEQ + s0 + kc2 * 32 + lk * 8);
                O[hf] = mfma16(pa[kc2], bv, O[hf]);
            }
    }
#pragma unroll
    for (int j = 0; j < 4; ++j) {
        float inv = 1.0f / l_[j];
        size_t rbase = (size_t)(qrow + lk * 4 + j) * D_EMB + h * HS;
#pragma unroll
        for (int hf = 0; hf < 8; ++hf)
            o[rbase + hf * 16 + lr] = f2bu(O[hf][j] * inv);
    }
}

// ---------------------------------------------------------------------------
extern "C" void kernel_launch(void* const* d_in, const int* in_sizes, int n_in,
                              void* d_out, int out_size, void* d_ws, size_t ws_size,
                              hipStream_t stream) {
    const int*   ids   = (const int*)d_in[0];
    const float* we    = (const float*)d_in[1];
    const float* pe    = (const float*)d_in[2];
    const float* Wq    = (const float*)d_in[3];
    const float* Wk    = (const float*)d_in[4];
    const float* Wv    = (const float*)d_in[5];
    const float* projw = (const float*)d_in[6];
    const float* projb = (const float*)d_in[7];
    const float* fcw   = (const float*)d_in[8];
    const float* fcb   = (const float*)d_in[9];
    float* out = (float*)d_out;
    (void)in_sizes; (void)n_in; (void)out_size; (void)ws_size;

    char* ws = (char*)d_ws;
    size_t off = 0;
    bfu*   fcwT  = (bfu*)(ws + off);  off += (size_t)NVOC * D_EMB * 2;   // 131 MB
    float* x32   = (float*)(ws + off); off += (size_t)T_SEQ * D_EMB * 4; // 16 MB
    bfu*   xb    = (bfu*)(ws + off);  off += (size_t)T_SEQ * D_EMB * 2;  // also attn-out
    bfu*   qb    = (bfu*)(ws + off);  off += (size_t)T_SEQ * D_EMB * 2;  // also resid
    bfu*   kb    = (bfu*)(ws + off);  off += (size_t)T_SEQ * D_EMB * 2;
    bfu*   vTb   = (bfu*)(ws + off);  off += (size_t)T_SEQ * D_EMB * 2;
    bfu*   WqT   = (bfu*)(ws + off);  off += (size_t)D_EMB * HS * NHEAD * 2;
    bfu*   WkT   = (bfu*)(ws + off);  off += (size_t)D_EMB * HS * NHEAD * 2;
    bfu*   WvT   = (bfu*)(ws + off);  off += (size_t)D_EMB * HS * NHEAD * 2;
    bfu*   projT = (bfu*)(ws + off);  off += (size_t)D_EMB * D_EMB * 2;  // ~205 MB total

    const float qscale = 0.08838834764831845f;  // 1/sqrt(HS), folded into WqT

    // weight transpose+convert (B^T-form bf16)
    k_transpose_cvt<<<dim3(HS / 64, D_EMB / 64, NHEAD), 256, 0, stream>>>(Wq, WqT, D_EMB, HS, qscale);
    k_transpose_cvt<<<dim3(HS / 64, D_EMB / 64, NHEAD), 256, 0, stream>>>(Wk, WkT, D_EMB, HS, 1.0f);
    k_transpose_cvt<<<dim3(HS / 64, D_EMB / 64, NHEAD), 256, 0, stream>>>(Wv, WvT, D_EMB, HS, 1.0f);
    k_transpose_cvt<<<dim3(D_EMB / 64, D_EMB / 64, 1), 256, 0, stream>>>(projw, projT, D_EMB, D_EMB, 1.0f);
    k_transpose_cvt<<<dim3(NVOC / 64, D_EMB / 64, 1), 256, 0, stream>>>(fcw, fcwT, D_EMB, NVOC, 1.0f);

    // x = we[ids] + pe
    k_embed<<<T_SEQ, 256, 0, stream>>>(ids, we, pe, x32, xb);

    // QKV projections (q pre-scaled via WqT)
    k_gemm_nt<0><<<(T_SEQ / 128) * (D_EMB / 128), 256, 0, stream>>>(xb, WqT, qb, nullptr, nullptr, T_SEQ, D_EMB, D_EMB);
    k_gemm_nt<0><<<(T_SEQ / 128) * (D_EMB / 128), 256, 0, stream>>>(xb, WkT, kb, nullptr, nullptr, T_SEQ, D_EMB, D_EMB);
    k_gemm_nt<0><<<(D_EMB / 128) * (T_SEQ / 128), 256, 0, stream>>>(WvT, xb, vTb, nullptr, nullptr, D_EMB, T_SEQ, D_EMB);

    // attention -> xb (cat layout [T][H*HS])
    k_attn<<<dim3(T_SEQ / 64, NHEAD), 256, 0, stream>>>(qb, kb, vTb, xb);

    // proj + bias + residual -> resid (bf16, into qb)
    k_gemm_nt<1><<<(T_SEQ / 128) * (D_EMB / 128), 256, 0, stream>>>(xb, projT, qb, projb, x32, T_SEQ, D_EMB, D_EMB);

    // final vocab GEMM: 256x256 8-phase kernel (f32 out + bias)
    k_gemm256<<<(T_SEQ / 256) * (NVOC / 256), 512, 0, stream>>>(qb, fcwT, out, fcb, T_SEQ, NVOC, D_EMB);
}

// Round 4
// 845.221 us; speedup vs baseline: 1.1337x; 1.0828x over previous
//
#include <hip/hip_runtime.h>

// Problem constants
#define T_SEQ 2048
#define D_EMB 2048
#define NHEAD 16
#define HS    128
#define NVOC  32000

typedef __attribute__((ext_vector_type(8))) short bf16x8;
typedef __attribute__((ext_vector_type(4))) float f32x4;
typedef unsigned short bfu;   // bf16 bits

__device__ __forceinline__ f32x4 mfma16(bf16x8 a, bf16x8 b, f32x4 c) {
    return __builtin_amdgcn_mfma_f32_16x16x32_bf16(a, b, c, 0, 0, 0);
}

// fp32 -> bf16 RNE
__device__ __forceinline__ bfu f2bu(float f) {
    unsigned int u = __float_as_uint(f);
    unsigned int r = (u + 0x7fffu + ((u >> 16) & 1u)) >> 16;
    return (bfu)r;
}

// async global->LDS, 16B per lane; lds base must be wave-uniform (HW adds lane*16)
__device__ __forceinline__ void async_copy16(void* lds, const void* g) {
    __builtin_amdgcn_global_load_lds(
        (const __attribute__((address_space(1))) unsigned int*)g,
        (__attribute__((address_space(3))) unsigned int*)lds, 16, 0, 0);
}

#define SB0 __builtin_amdgcn_sched_barrier(0)
#define BARRIER __builtin_amdgcn_s_barrier()
#define WAIT_LGKM0 asm volatile("s_waitcnt lgkmcnt(0)" ::: "memory")
#define WAIT_VM8   asm volatile("s_waitcnt vmcnt(8)" ::: "memory")
#define WAIT_VM6   asm volatile("s_waitcnt vmcnt(6)" ::: "memory")
#define WAIT_VM4   asm volatile("s_waitcnt vmcnt(4)" ::: "memory")
#define WAIT_VM2   asm volatile("s_waitcnt vmcnt(2)" ::: "memory")
#define WAIT_VM0   asm volatile("s_waitcnt vmcnt(0)" ::: "memory")

// ---------------------------------------------------------------------------
// x = we[ids] + pe ; also bf16 copy.  grid = T_SEQ blocks x 256
// ---------------------------------------------------------------------------
__global__ void k_embed(const int* __restrict__ ids, const float* __restrict__ we,
                        const float* __restrict__ pe, float* __restrict__ x,
                        bfu* __restrict__ xb) {
    const int t = blockIdx.x;
    const int row = ids[t];
    const float4* wr = (const float4*)(we + (size_t)row * D_EMB);
    const float4* pr = (const float4*)(pe + (size_t)t * D_EMB);
    float4* xr = (float4*)(x + (size_t)t * D_EMB);
    bfu* xbr = xb + (size_t)t * D_EMB;
    int i = threadIdx.x;
#pragma unroll
    for (int r = 0; r < 2; ++r, i += 256) {
        float4 a = wr[i], b = pr[i];
        float4 s; s.x = a.x + b.x; s.y = a.y + b.y; s.z = a.z + b.z; s.w = a.w + b.w;
        xr[i] = s;
        ushort4 u; u.x = f2bu(s.x); u.y = f2bu(s.y); u.z = f2bu(s.z); u.w = f2bu(s.w);
        *(ushort4*)(xbr + i * 4) = u;
    }
}

// ---------------------------------------------------------------------------
// Transpose+convert: in fp32 [R][C] -> out bf16 [C][R], scaled. Batched on z.
// ---------------------------------------------------------------------------
__global__ void k_transpose_cvt(const float* __restrict__ in, bfu* __restrict__ out,
                                int R, int C, float scale) {
    __shared__ float tile[64][65];
    const int z = blockIdx.z;
    in  += (size_t)z * R * C;
    out += (size_t)z * R * C;
    const int r0 = blockIdx.y * 64, c0 = blockIdx.x * 64;
    const int t = threadIdx.x;
#pragma unroll
    for (int it = 0; it < 4; ++it) {
        int fi = it * 256 + t;
        int row = fi >> 4, c4 = (fi & 15) * 4;
        float4 v = *(const float4*)(in + (size_t)(r0 + row) * C + c0 + c4);
        tile[row][c4]     = v.x; tile[row][c4 + 1] = v.y;
        tile[row][c4 + 2] = v.z; tile[row][c4 + 3] = v.w;
    }
    __syncthreads();
#pragma unroll
    for (int it = 0; it < 4; ++it) {
        int ci = it * 256 + t;
        int oc = ci >> 4, r4 = (ci & 15) * 4;
        ushort4 u;
        u.x = f2bu(tile[r4 + 0][oc] * scale);
        u.y = f2bu(tile[r4 + 1][oc] * scale);
        u.z = f2bu(tile[r4 + 2][oc] * scale);
        u.w = f2bu(tile[r4 + 3][oc] * scale);
        *(ushort4*)(out + (size_t)(c0 + oc) * R + r0 + r4) = u;
    }
}

// ---------------------------------------------------------------------------
// GEMM (m97-style 128x128) C[M][N] = A[M][K] * Bt[N][K]^T
// EPI: 0 = bf16 out; 1 = bf16 out + bias[col] + res32[idx]; 2 = f32 out + bias
// ---------------------------------------------------------------------------
template <int EPI>
__global__ __launch_bounds__(256, 2)
void k_gemm_nt(const bfu* __restrict__ A, const bfu* __restrict__ Bt,
               void* __restrict__ Cv, const float* __restrict__ bias,
               const float* __restrict__ res32, int M, int N, int K) {
    __shared__ __align__(16) char smem[2 * 128 * 64 * 2];
    const int tid = threadIdx.x;
    const int w = tid >> 6, lane = tid & 63;
    const int wr = w >> 1, wc = w & 1;
    const int lr = lane & 15, lk = lane >> 4;   // lk in 0..3
    const int mb = M >> 7;
    const int m0 = (blockIdx.x % mb) << 7;
    const int n0 = (blockIdx.x / mb) << 7;
    char* As = smem;
    char* Bs = smem + 16384;
    f32x4 acc[4][4];
#pragma unroll
    for (int i = 0; i < 4; ++i)
#pragma unroll
        for (int j = 0; j < 4; ++j) acc[i][j] = (f32x4){0.f, 0.f, 0.f, 0.f};

    const bfu* Ag = A + (size_t)m0 * K;
    const bfu* Bg = Bt + (size_t)n0 * K;

    for (int kk = 0; kk < K; kk += 64) {
        __syncthreads();
#pragma unroll
        for (int r = 0; r < 4; ++r) {
            int i = r * 256 + tid;                       // lane-load index
            async_copy16(As + (r * 256 + w * 64) * 16,
                         Ag + (size_t)(i >> 3) * K + kk + (i & 7) * 8);
        }
#pragma unroll
        for (int r = 0; r < 4; ++r) {
            int i = r * 256 + tid;
            async_copy16(Bs + (r * 256 + w * 64) * 16,
                         Bg + (size_t)(i >> 3) * K + kk + (i & 7) * 8);
        }
        __syncthreads();
#pragma unroll
        for (int kc = 0; kc < 2; ++kc) {
            bf16x8 a[4], b[4];
#pragma unroll
            for (int mf = 0; mf < 4; ++mf)
                a[mf] = *(const bf16x8*)(As + ((wr * 64 + mf * 16 + lr) * 64 + kc * 32 + lk * 8) * 2);
#pragma unroll
            for (int nf = 0; nf < 4; ++nf)
                b[nf] = *(const bf16x8*)(Bs + ((wc * 64 + nf * 16 + lr) * 64 + kc * 32 + lk * 8) * 2);
#pragma unroll
            for (int mf = 0; mf < 4; ++mf)
#pragma unroll
                for (int nf = 0; nf < 4; ++nf)
                    acc[mf][nf] = mfma16(a[mf], b[nf], acc[mf][nf]);
        }
    }
#pragma unroll
    for (int nf = 0; nf < 4; ++nf) {
        int col = n0 + wc * 64 + nf * 16 + lr;
        float bv = (EPI >= 1) ? bias[col] : 0.0f;
#pragma unroll
        for (int mf = 0; mf < 4; ++mf) {
            int row0 = m0 + wr * 64 + mf * 16 + lk * 4;
            f32x4 v = acc[mf][nf];
#pragma unroll
            for (int j = 0; j < 4; ++j) {
                size_t idx = (size_t)(row0 + j) * N + col;
                float val = v[j] + bv;
                if (EPI == 1) val += res32[idx];
                if (EPI == 2) ((float*)Cv)[idx] = val;
                else          ((bfu*)Cv)[idx] = f2bu(val);
            }
        }
    }
}

// ---------------------------------------------------------------------------
// 256x256 8-phase GEMM (T1+T2+T3+T4+T5), f32 out + bias.
// LDS swizzle (round-4 fix): full 3-bit involution slot ^= (row&7) within
// each 128-B row — spreads each ds_read_b128 over all 32 banks (8 lanes per
// 16-B slot = the structural wave64 minimum). Stage keeps LDS dest linear
// and pre-permutes the GLOBAL source slot by the same involution.
// vmcnt FIFO schedule + tail peel identical to round 3 (verified correct).
// ---------------------------------------------------------------------------
__device__ __forceinline__ void stage_chunk(char* sm, const bfu* A_, const bfu* B_,
                                            int K, int tt, int kind, int w,
                                            int laneRow, int laneCol) {
    // kind: 0=A-q0 (rows 0-63,128-191), 1=A-q1 (64-127,192-255),
    //       2=B-q0 (rows x*64+[0,32)), 3=B-q1 (rows x*64+[32,64))
    char* base = sm + (size_t)(tt & 1) * 65536 + ((kind >= 2) ? 32768 : 0);
    const bfu* G = (kind >= 2) ? B_ : A_;
#pragma unroll
    for (int r = 0; r < 2; ++r) {
        int p = w * 2 + r;
        int row0 = (kind < 2) ? ((kind & 1) * 64 + (p & 7) * 8 + (p >> 3) * 128)
                              : ((kind & 1) * 32 + (p & 3) * 8 + (p >> 2) * 64);
        const char* g = (const char*)G + ((size_t)(row0 + laneRow) * K + tt * 64) * 2 + laneCol;
        async_copy16(base + row0 * 128, g);
    }
}

template <int Q>
__device__ __forceinline__ void read_A(bf16x8 (&aA)[2][4][2], const char* bufA,
                                       int wm, int lr, int sw0) {
    const char* p = bufA + ((wm * 128 + Q * 64 + lr) * 128);
#pragma unroll
    for (int mf = 0; mf < 4; ++mf) {
        aA[Q][mf][0] = *(const bf16x8*)(p + mf * 2048 + sw0);
        aA[Q][mf][1] = *(const bf16x8*)(p + mf * 2048 + (sw0 ^ 64));
    }
}

template <int Q>
__device__ __forceinline__ void read_B(bf16x8 (&bB)[2][2], const char* bufB,
                                       int wn, int lr, int sw0) {
    const char* p = bufB + ((wn * 64 + Q * 32 + lr) * 128);
#pragma unroll
    for (int nf = 0; nf < 2; ++nf) {
        bB[nf][0] = *(const bf16x8*)(p + nf * 2048 + sw0);
        bB[nf][1] = *(const bf16x8*)(p + nf * 2048 + (sw0 ^ 64));
    }
}

template <int QM, int QN>
__device__ __forceinline__ void mfma_quad(f32x4 (&acc)[8][4], bf16x8 (&aA)[2][4][2],
                                          bf16x8 (&bB)[2][2]) {
    __builtin_amdgcn_s_setprio(1);
#pragma unroll
    for (int mf = 0; mf < 4; ++mf)
#pragma unroll
        for (int nf = 0; nf < 2; ++nf)
#pragma unroll
            for (int kc = 0; kc < 2; ++kc)
                acc[QM * 4 + mf][QN * 2 + nf] =
                    mfma16(aA[QM][mf][kc], bB[nf][kc], acc[QM * 4 + mf][QN * 2 + nf]);
    __builtin_amdgcn_s_setprio(0);
}

__global__ __launch_bounds__(512, 2)
void k_gemm256(const bfu* __restrict__ A, const bfu* __restrict__ Bt,
               float* __restrict__ C, const float* __restrict__ bias,
               int M, int N, int K) {
    __shared__ __align__(16) char smem[2 * 65536];   // 128 KiB
    const int tid = threadIdx.x;
    const int w = tid >> 6, lane = tid & 63;
    const int wm = w >> 2, wn = w & 3;
    const int lr = lane & 15, lk = lane >> 4;
    const int sw0 = ((lk ^ (lr & 7)) << 4);                 // read-side swizzle
    const int laneRow = lane >> 3;
    const int laneCol = ((lane & 7) ^ (lane >> 3)) << 4;    // stage-side (global src) swizzle

    // XCD-aware bijective block swizzle (nwgs % 8 == 0 for our launch)
    const int mb = M >> 8;
    const int nwgs = mb * (N >> 8);
    int bid = blockIdx.x;
    int swz = ((nwgs & 7) == 0) ? ((bid & 7) * (nwgs >> 3) + (bid >> 3)) : bid;
    const int m0 = (swz % mb) << 8;
    const int n0 = (swz / mb) << 8;

    const bfu* Ag = A + (size_t)m0 * K;
    const bfu* Bg = Bt + (size_t)n0 * K;

    f32x4 acc[8][4];
#pragma unroll
    for (int i = 0; i < 8; ++i)
#pragma unroll
        for (int j = 0; j < 4; ++j) acc[i][j] = (f32x4){0.f, 0.f, 0.f, 0.f};
    bf16x8 aA[2][4][2], bB[2][2];

    const int nkt = K >> 6;   // requires nkt >= 4

    // prologue: tile0 all chunks (oldest-first = first-consumed), tile1 B0,A0
    stage_chunk(smem, Ag, Bg, K, 0, 0, w, laneRow, laneCol);
    stage_chunk(smem, Ag, Bg, K, 0, 2, w, laneRow, laneCol);
    stage_chunk(smem, Ag, Bg, K, 0, 1, w, laneRow, laneCol);
    stage_chunk(smem, Ag, Bg, K, 0, 3, w, laneRow, laneCol);
    stage_chunk(smem, Ag, Bg, K, 1, 2, w, laneRow, laneCol);
    stage_chunk(smem, Ag, Bg, K, 1, 0, w, laneRow, laneCol);
    WAIT_VM8; SB0; BARRIER;

    for (int t = 0; t < nkt - 2; ++t) {
        const char* bufA = smem + (size_t)(t & 1) * 65536;
        const char* bufB = bufA + 32768;
        // P0
        read_A<0>(aA, bufA, wm, lr, sw0);
        read_B<0>(bB, bufB, wn, lr, sw0);
        stage_chunk(smem, Ag, Bg, K, t + 1, 1, w, laneRow, laneCol);
        SB0; BARRIER; WAIT_LGKM0; SB0;
        mfma_quad<0, 0>(acc, aA, bB);
        WAIT_VM8; SB0; BARRIER;
        // P1
        read_A<1>(aA, bufA, wm, lr, sw0);
        stage_chunk(smem, Ag, Bg, K, t + 1, 3, w, laneRow, laneCol);
        SB0; BARRIER; WAIT_LGKM0; SB0;
        mfma_quad<1, 0>(acc, aA, bB);
        WAIT_VM8; SB0; BARRIER;
        // P2
        read_B<1>(bB, bufB, wn, lr, sw0);
        stage_chunk(smem, Ag, Bg, K, t + 2, 2, w, laneRow, laneCol);
        SB0; BARRIER; WAIT_LGKM0; SB0;
        mfma_quad<0, 1>(acc, aA, bB);
        WAIT_VM8; SB0; BARRIER;
        // P3
        stage_chunk(smem, Ag, Bg, K, t + 2, 0, w, laneRow, laneCol);
        SB0; BARRIER; SB0;
        mfma_quad<1, 1>(acc, aA, bB);
        WAIT_VM8; SB0; BARRIER;
    }

    {   // t = nkt-2: stages only t+1; waits 8,8,6,4
        const int t = nkt - 2;
        const char* bufA = smem + (size_t)(t & 1) * 65536;
        const char* bufB = bufA + 32768;
        read_A<0>(aA, bufA, wm, lr, sw0);
        read_B<0>(bB, bufB, wn, lr, sw0);
        stage_chunk(smem, Ag, Bg, K, t + 1, 1, w, laneRow, laneCol);
        SB0; BARRIER; WAIT_LGKM0; SB0;
        mfma_quad<0, 0>(acc, aA, bB);
        WAIT_VM8; SB0; BARRIER;

        read_A<1>(aA, bufA, wm, lr, sw0);
        stage_chunk(smem, Ag, Bg, K, t + 1, 3, w, laneRow, laneCol);
        SB0; BARRIER; WAIT_LGKM0; SB0;
        mfma_quad<1, 0>(acc, aA, bB);
        WAIT_VM8; SB0; BARRIER;

        read_B<1>(bB, bufB, wn, lr, sw0);
        SB0; BARRIER; WAIT_LGKM0; SB0;
        mfma_quad<0, 1>(acc, aA, bB);
        WAIT_VM6; SB0; BARRIER;

        SB0;
        mfma_quad<1, 1>(acc, aA, bB);
        WAIT_VM4; SB0; BARRIER;
    }
    {   // t = nkt-1: drain; waits 2,0
        const int t = nkt - 1;
        const char* bufA = smem + (size_t)(t & 1) * 65536;
        const char* bufB = bufA + 32768;
        read_A<0>(aA, bufA, wm, lr, sw0);
        read_B<0>(bB, bufB, wn, lr, sw0);
        SB0; BARRIER; WAIT_LGKM0; SB0;
        mfma_quad<0, 0>(acc, aA, bB);
        WAIT_VM2; SB0; BARRIER;

        read_A<1>(aA, bufA, wm, lr, sw0);
        SB0; BARRIER; WAIT_LGKM0; SB0;
        mfma_quad<1, 0>(acc, aA, bB);
        WAIT_VM0; SB0; BARRIER;

        read_B<1>(bB, bufB, wn, lr, sw0);
        SB0; WAIT_LGKM0; SB0;
        mfma_quad<0, 1>(acc, aA, bB);
        mfma_quad<1, 1>(acc, aA, bB);
    }

    // epilogue: f32 + bias
#pragma unroll
    for (int nfg = 0; nfg < 4; ++nfg) {
        int col = n0 + wn * 64 + nfg * 16 + lr;
        float bv = bias[col];
#pragma unroll
        for (int mfg = 0; mfg < 8; ++mfg) {
            int row0 = m0 + wm * 128 + mfg * 16 + lk * 4;
            f32x4 v = acc[mfg][nfg];
#pragma unroll
            for (int j = 0; j < 4; ++j)
                C[(size_t)(row0 + j) * N + col] = v[j] + bv;
        }
    }
}

// ---------------------------------------------------------------------------
// Flash attention (causal). q,k: bf16 with row stride qks (scale folded into
// q via WqT). vT: [H*HS][T] bf16. out: [T][H*HS] bf16.
// ---------------------------------------------------------------------------
__global__ __launch_bounds__(256, 2)
void k_attn(const bfu* __restrict__ q, const bfu* __restrict__ k,
            const bfu* __restrict__ vT, bfu* __restrict__ o, int qks) {
    __shared__ __align__(16) bfu plds[4][16][72];   // per-wave P tile, padded stride
    const int w = threadIdx.x >> 6, lane = threadIdx.x & 63;
    const int lr = lane & 15, lk = lane >> 4;
    const int h = blockIdx.y;
    const int qrow = blockIdx.x * 64 + w * 16;

    bf16x8 aq[4];
#pragma unroll
    for (int kc = 0; kc < 4; ++kc)
        aq[kc] = *(const bf16x8*)(q + (size_t)(qrow + lr) * qks + h * HS + kc * 32 + lk * 8);

    f32x4 O[8];
#pragma unroll
    for (int hf = 0; hf < 8; ++hf) O[hf] = (f32x4){0.f, 0.f, 0.f, 0.f};
    float m_[4], l_[4];
#pragma unroll
    for (int j = 0; j < 4; ++j) { m_[j] = -__builtin_inff(); l_[j] = 0.f; }

    const int nst = (qrow + 15) / 64 + 1;
    for (int st = 0; st < nst; ++st) {
        const int s0 = st * 64;
        f32x4 S[4];
#pragma unroll
        for (int nf = 0; nf < 4; ++nf) S[nf] = (f32x4){0.f, 0.f, 0.f, 0.f};
#pragma unroll
        for (int nf = 0; nf < 4; ++nf)
#pragma unroll
            for (int kc = 0; kc < 4; ++kc) {
                bf16x8 bk = *(const bf16x8*)(k + (size_t)(s0 + nf * 16 + lr) * qks + h * HS + kc * 32 + lk * 8);
                S[nf] = mfma16(aq[kc], bk, S[nf]);
            }
        if (s0 + 63 > qrow) {
#pragma unroll
            for (int nf = 0; nf < 4; ++nf) {
                int scol = s0 + nf * 16 + lr;
#pragma unroll
                for (int j = 0; j < 4; ++j)
                    if (scol > qrow + lk * 4 + j) S[nf][j] = -1e30f;
            }
        }
        float tm[4];
#pragma unroll
        for (int j = 0; j < 4; ++j)
            tm[j] = fmaxf(fmaxf(S[0][j], S[1][j]), fmaxf(S[2][j], S[3][j]));
#pragma unroll
        for (int d = 1; d < 16; d <<= 1)
#pragma unroll
            for (int j = 0; j < 4; ++j) tm[j] = fmaxf(tm[j], __shfl_xor(tm[j], d));
        float mn[4], ts[4];
#pragma unroll
        for (int j = 0; j < 4; ++j) mn[j] = fmaxf(m_[j], tm[j]);
#pragma unroll
        for (int nf = 0; nf < 4; ++nf)
#pragma unroll
            for (int j = 0; j < 4; ++j) S[nf][j] = __expf(S[nf][j] - mn[j]);
#pragma unroll
        for (int j = 0; j < 4; ++j) ts[j] = S[0][j] + S[1][j] + S[2][j] + S[3][j];
#pragma unroll
        for (int d = 1; d < 16; d <<= 1)
#pragma unroll
            for (int j = 0; j < 4; ++j) ts[j] += __shfl_xor(ts[j], d);
#pragma unroll
        for (int nf = 0; nf < 4; ++nf)
#pragma unroll
            for (int j = 0; j < 4; ++j)
                plds[w][lk * 4 + j][nf * 16 + lr] = f2bu(S[nf][j]);
#pragma unroll
        for (int j = 0; j < 4; ++j) {
            float f = __expf(m_[j] - mn[j]);
            l_[j] = l_[j] * f + ts[j];
            m_[j] = mn[j];
#pragma unroll
            for (int hf = 0; hf < 8; ++hf) O[hf][j] *= f;
        }
        bf16x8 pa[2];
#pragma unroll
        for (int kc2 = 0; kc2 < 2; ++kc2)
            pa[kc2] = *(const bf16x8*)(&plds[w][lr][kc2 * 32 + lk * 8]);
#pragma unroll
        for (int hf = 0; hf < 8; ++hf)
#pragma unroll
            for (int kc2 = 0; kc2 < 2; ++kc2) {
                bf16x8 bv = *(const bf16x8*)(vT + (size_t)(h * HS + hf * 16 + lr) * T_SEQ + s0 + kc2 * 32 + lk * 8);
                O[hf] = mfma16(pa[kc2], bv, O[hf]);
            }
    }
#pragma unroll
    for (int j = 0; j < 4; ++j) {
        float inv = 1.0f / l_[j];
        size_t rbase = (size_t)(qrow + lk * 4 + j) * D_EMB + h * HS;
#pragma unroll
        for (int hf = 0; hf < 8; ++hf)
            o[rbase + hf * 16 + lr] = f2bu(O[hf][j] * inv);
    }
}

// ---------------------------------------------------------------------------
extern "C" void kernel_launch(void* const* d_in, const int* in_sizes, int n_in,
                              void* d_out, int out_size, void* d_ws, size_t ws_size,
                              hipStream_t stream) {
    const int*   ids   = (const int*)d_in[0];
    const float* we    = (const float*)d_in[1];
    const float* pe    = (const float*)d_in[2];
    const float* Wq    = (const float*)d_in[3];
    const float* Wk    = (const float*)d_in[4];
    const float* Wv    = (const float*)d_in[5];
    const float* projw = (const float*)d_in[6];
    const float* projb = (const float*)d_in[7];
    const float* fcw   = (const float*)d_in[8];
    const float* fcb   = (const float*)d_in[9];
    float* out = (float*)d_out;
    (void)in_sizes; (void)n_in; (void)out_size; (void)ws_size;

    char* ws = (char*)d_ws;
    size_t off = 0;
    bfu*   fcwT  = (bfu*)(ws + off);  off += (size_t)NVOC * D_EMB * 2;   // 131 MB
    float* x32   = (float*)(ws + off); off += (size_t)T_SEQ * D_EMB * 4; // 16 MB
    bfu*   xb    = (bfu*)(ws + off);  off += (size_t)T_SEQ * D_EMB * 2;  // also attn-out
    bfu*   qkb   = (bfu*)(ws + off);  off += (size_t)T_SEQ * 2 * D_EMB * 2; // q|k combined [T][4096]
    bfu*   resb  = (bfu*)(ws + off);  off += (size_t)T_SEQ * D_EMB * 2;  // resid bf16
    bfu*   vTb   = (bfu*)(ws + off);  off += (size_t)T_SEQ * D_EMB * 2;
    bfu*   WqT   = (bfu*)(ws + off);  off += (size_t)D_EMB * HS * NHEAD * 2;  // WqT|WkT contiguous
    bfu*   WkT   = (bfu*)(ws + off);  off += (size_t)D_EMB * HS * NHEAD * 2;
    bfu*   WvT   = (bfu*)(ws + off);  off += (size_t)D_EMB * HS * NHEAD * 2;
    bfu*   projT = (bfu*)(ws + off);  off += (size_t)D_EMB * D_EMB * 2;  // ~213 MB total

    const float qscale = 0.08838834764831845f;  // 1/sqrt(HS), folded into WqT

    // weight transpose+convert (B^T-form bf16)
    k_transpose_cvt<<<dim3(HS / 64, D_EMB / 64, NHEAD), 256, 0, stream>>>(Wq, WqT, D_EMB, HS, qscale);
    k_transpose_cvt<<<dim3(HS / 64, D_EMB / 64, NHEAD), 256, 0, stream>>>(Wk, WkT, D_EMB, HS, 1.0f);
    k_transpose_cvt<<<dim3(HS / 64, D_EMB / 64, NHEAD), 256, 0, stream>>>(Wv, WvT, D_EMB, HS, 1.0f);
    k_transpose_cvt<<<dim3(D_EMB / 64, D_EMB / 64, 1), 256, 0, stream>>>(projw, projT, D_EMB, D_EMB, 1.0f);
    k_transpose_cvt<<<dim3(NVOC / 64, D_EMB / 64, 1), 256, 0, stream>>>(fcw, fcwT, D_EMB, NVOC, 1.0f);

    // x = we[ids] + pe
    k_embed<<<T_SEQ, 256, 0, stream>>>(ids, we, pe, x32, xb);

    // Q and K projections fused (WqT|WkT contiguous -> N=4096), V transposed
    k_gemm_nt<0><<<(T_SEQ / 128) * (2 * D_EMB / 128), 256, 0, stream>>>(xb, WqT, qkb, nullptr, nullptr, T_SEQ, 2 * D_EMB, D_EMB);
    k_gemm_nt<0><<<(D_EMB / 128) * (T_SEQ / 128), 256, 0, stream>>>(WvT, xb, vTb, nullptr, nullptr, D_EMB, T_SEQ, D_EMB);

    // attention -> xb (cat layout [T][H*HS]); q = qkb[:, :2048], k = qkb[:, 2048:]
    k_attn<<<dim3(T_SEQ / 64, NHEAD), 256, 0, stream>>>(qkb, qkb + D_EMB, vTb, xb, 2 * D_EMB);

    // proj + bias + residual -> resid (bf16)
    k_gemm_nt<1><<<(T_SEQ / 128) * (D_EMB / 128), 256, 0, stream>>>(xb, projT, resb, projb, x32, T_SEQ, D_EMB, D_EMB);

    // final vocab GEMM: 256x256 8-phase kernel (f32 out + bias)
    k_gemm256<<<(T_SEQ / 256) * (NVOC / 256), 512, 0, stream>>>(resb, fcwT, out, fcb, T_SEQ, NVOC, D_EMB);
}